// Round 6
// baseline (67.117 us; speedup 1.0000x reference)
//
#include <hip/hip_runtime.h>
#include <hip/hip_bf16.h>
#include <hip/hip_cooperative_groups.h>

namespace cg = cooperative_groups;

// out = sigmoid( g0*w0 + g1*(X@w1) + g2*f2 + g3*f3 ), D=64, N=8192
// f3 via GEMM: monomial {a<=b<=c} w -> W[pair(b,c), a]; f3[n] = sum_p y_p * (X@W^T)[n,p], y_p = x_j x_k
// f2 folded into epilogue: part += (g3*S[n,p] + g2*w2eff[p]) * y_p
// R6: ONE cooperative kernel (build -> grid.sync -> poly); pointer-induction B-path;
//     epilogue LDS reads software-pipelined one iteration ahead.

#define DD 64
#define NPAIR 2080
#define NTILES 130
#define PTILES 146   // 130 real + 16 zero dummy tiles (branchless 2-deep prefetch, max idx 145)

typedef __attribute__((ext_vector_type(8))) short short8;
typedef __attribute__((ext_vector_type(4))) float f32x4;

// ws layout (bytes)
#define W_OFF  0u         // bf16 packed [146][2][64][8] = 299008
#define E_OFF  299008u    // float2 {g2*w2eff, jk} [146*16] = 18688

__device__ __forceinline__ short f2bf(float v) {
    __hip_bfloat16 h = __float2bfloat16(v);
    return (short)__builtin_bit_cast(unsigned short, h);
}

__device__ __forceinline__ void compute_gates(const float* __restrict__ alpha,
                                              float& g0, float& g1, float& g2, float& g3) {
    float a0 = alpha[0], a1 = alpha[1], a2 = alpha[2], a3 = alpha[3];
    float m = fmaxf(fmaxf(a0, a1), fmaxf(a2, a3));
    float e0 = __expf(a0 - m), e1 = __expf(a1 - m);
    float e2 = __expf(a2 - m), e3 = __expf(a3 - m);
    float inv = 1.0f / (e0 + e1 + e2 + e3);
    g0 = e0 * inv; g1 = e1 * inv; g2 = e2 * inv; g3 = e3 * inv;
}

// 256 blocks x 512 thr (8 waves). Block owns 32 samples. Blocks 0..145 also build W tile blockIdx.
__global__ __launch_bounds__(512) void fused_kernel(
    const float* __restrict__ X,
    const float* __restrict__ w0,
    const float* __restrict__ w1,
    const float* __restrict__ w2,
    const float* __restrict__ w3,
    const float* __restrict__ alpha,
    short* __restrict__ Wp,
    float2* __restrict__ et,
    float* __restrict__ out)
{
    __shared__ float xs[DD][36];     // transposed tile: xs[dim][sample]
    __shared__ float red[8][32];
    __shared__ float f1s[32];

    const int tid = threadIdx.x;
    const int lane = tid & 63, wv = tid >> 6;
    const int s0 = blockIdx.x * 32;

    float g0, g1, g2, g3;
    compute_gates(alpha, g0, g1, g2, g3);

    // ---------- phase 1: build packed W tile blockIdx (threads 0..127) ----------
    if (blockIdx.x < PTILES && tid < 128) {
        const int nt = blockIdx.x;
        const int half = tid >> 6, fl = tid & 63;
        const int brow = fl & 15, bkg = fl >> 4;
        const int row = nt * 16 + brow;              // pair row
        const int kb = half * 32 + bkg * 8;          // first col of this 8-group
        const int pko = nt * 1024 + tid * 8;

        if (row >= NPAIR) {                          // zero dummy tiles
            short8 z = {0, 0, 0, 0, 0, 0, 0, 0};
            *(short8*)(Wp + pko) = z;
            if (half == 0 && bkg == 0) { float2 zv; zv.x = 0.0f; zv.y = __uint_as_float(0u); et[row] = zv; }
        } else {
            int j = 0, r2 = row;                     // decode pair row -> (j<=k)
            while (r2 >= 64 - j) { r2 -= 64 - j; ++j; }
            const int k = j + r2;
            short8 v;
            #pragma unroll
            for (int e = 0; e < 8; ++e) {
                const int a = kb + e;                // monomial smallest index
                float w = 0.0f;
                if (a <= j) {
                    if (a == j) {
                        w = (j == k) ? w3[j]
                                     : w3[64 + 63 * j - (j * (j - 1)) / 2 + (k - j - 1)];
                    } else if (j == k) {
                        w = w3[64 + 2016 + 63 * a - (a * (a - 1)) / 2 + (j - a - 1)];
                    } else {
                        const int tb = 41664 - ((64 - a) * (63 - a) * (62 - a)) / 6;
                        const int po = ((62 - a + 64 - j) * (j - a - 1)) / 2 + (k - j - 1);
                        w = w3[4096 + tb + po];
                    }
                }
                v[e] = f2bf(w);
            }
            *(short8*)(Wp + pko) = v;
            if (half == 0 && bkg == 0) {
                float w2e = (j == k) ? w2[j] : w2[64 + 63 * j - (j * (j - 1)) / 2 + (k - j - 1)];
                float2 ev;
                ev.x = g2 * w2e;
                ev.y = __uint_as_float(((unsigned)j << 8) | (unsigned)k);
                et[row] = ev;
            }
        }
        __threadfence();                             // device-scope release of Wp/et
    }

    // ---------- stage X tile + A-fragments (overlaps builders' work) ----------
    for (int idx = tid; idx < 32 * 64; idx += 512) {
        xs[idx & 63][idx >> 6] = X[(size_t)s0 * 64 + idx];
    }
    const int arow = lane & 15, akg = lane >> 4;
    const float* xr0 = X + (size_t)(s0 + arow) * 64 + 8 * akg;
    const float* xr1 = X + (size_t)(s0 + 16 + arow) * 64 + 8 * akg;
    short8 a0m0, a1m0, a0m1, a1m1;
    {
        f32x4 p0 = *(const f32x4*)(xr0);
        f32x4 p1 = *(const f32x4*)(xr0 + 4);
        f32x4 q0 = *(const f32x4*)(xr0 + 32);
        f32x4 q1 = *(const f32x4*)(xr0 + 36);
        f32x4 r0 = *(const f32x4*)(xr1);
        f32x4 r1 = *(const f32x4*)(xr1 + 4);
        f32x4 s0v = *(const f32x4*)(xr1 + 32);
        f32x4 s1v = *(const f32x4*)(xr1 + 36);
        #pragma unroll
        for (int e = 0; e < 4; ++e) {
            a0m0[e] = f2bf(p0[e]); a0m0[4 + e] = f2bf(p1[e]);
            a1m0[e] = f2bf(q0[e]); a1m0[4 + e] = f2bf(q1[e]);
            a0m1[e] = f2bf(r0[e]); a0m1[4 + e] = f2bf(r1[e]);
            a1m1[e] = f2bf(s0v[e]); a1m1[4 + e] = f2bf(s1v[e]);
        }
    }

    cg::this_grid().sync();                          // build visible; also block-level barrier for xs

    // ---------- phase 2: GEMM + fused epilogue ----------
    // slots: A = nt (compute), B = nt+8 (next), C = nt+16 (prefetch). Dummy tiles are zeros.
    const short* wb = Wp + wv * 1024 + lane * 8;
    const float2* ep = et + wv * 16 + arow;

    short8 bA0 = *(const short8*)wb;
    short8 bA1 = *(const short8*)(wb + 512);
    float2 eA = *ep;
    short8 bB0 = *(const short8*)(wb + 8192);
    short8 bB1 = *(const short8*)(wb + 8192 + 512);
    float2 eB = *(ep + 128);
    wb += 16384; ep += 256;

    unsigned jkA = __float_as_uint(eA.y);
    float bpA = eA.x;
    f32x4 xj0 = *(const f32x4*)&xs[jkA >> 8][4 * akg];
    f32x4 xk0 = *(const f32x4*)&xs[jkA & 255][4 * akg];
    f32x4 xj1 = *(const f32x4*)&xs[jkA >> 8][16 + 4 * akg];
    f32x4 xk1 = *(const f32x4*)&xs[jkA & 255][16 + 4 * akg];

    float part0[4] = {0, 0, 0, 0}, part1[4] = {0, 0, 0, 0};
    const int niter = (NTILES - wv + 7) >> 3;        // 16 or 17

    #pragma unroll 2
    for (int it = 0; it < niter; ++it) {
        short8 bC0 = *(const short8*)wb;             // prefetch slot C
        short8 bC1 = *(const short8*)(wb + 512);
        float2 eC = *ep;
        wb += 8192; ep += 128;

        const unsigned jkB = __float_as_uint(eB.y);  // pipeline next iter's LDS reads
        const float bpB = eB.x;
        f32x4 nxj0 = *(const f32x4*)&xs[jkB >> 8][4 * akg];
        f32x4 nxk0 = *(const f32x4*)&xs[jkB & 255][4 * akg];
        f32x4 nxj1 = *(const f32x4*)&xs[jkB >> 8][16 + 4 * akg];
        f32x4 nxk1 = *(const f32x4*)&xs[jkB & 255][16 + 4 * akg];

        f32x4 c0 = {0, 0, 0, 0}, c1 = {0, 0, 0, 0};
        c0 = __builtin_amdgcn_mfma_f32_16x16x32_bf16(a0m0, bA0, c0, 0, 0, 0);
        c0 = __builtin_amdgcn_mfma_f32_16x16x32_bf16(a1m0, bA1, c0, 0, 0, 0);
        c1 = __builtin_amdgcn_mfma_f32_16x16x32_bf16(a0m1, bA0, c1, 0, 0, 0);
        c1 = __builtin_amdgcn_mfma_f32_16x16x32_bf16(a1m1, bA1, c1, 0, 0, 0);

        #pragma unroll
        for (int r = 0; r < 4; ++r) {
            float t0 = fmaf(g3, c0[r], bpA);
            part0[r] = fmaf(t0, xj0[r] * xk0[r], part0[r]);
            float t1 = fmaf(g3, c1[r], bpA);
            part1[r] = fmaf(t1, xj1[r] * xk1[r], part1[r]);
        }

        bA0 = bB0; bA1 = bB1; bB0 = bC0; bB1 = bC1;
        bpA = bpB; eB = eC;
        xj0 = nxj0; xk0 = nxk0; xj1 = nxj1; xk1 = nxk1;
    }

    // reduce across the 16 pair-columns (lane bits 0..3)
    #pragma unroll
    for (int r = 0; r < 4; ++r) {
        float v0 = part0[r], v1 = part1[r];
        for (int m = 1; m <= 8; m <<= 1) {
            v0 += __shfl_xor(v0, m, 64);
            v1 += __shfl_xor(v1, m, 64);
        }
        part0[r] = v0; part1[r] = v1;
    }
    if ((lane & 15) == 0) {
        const int rb = 4 * (lane >> 4);
        #pragma unroll
        for (int r = 0; r < 4; ++r) {
            red[wv][rb + r] = part0[r];
            red[wv][16 + rb + r] = part1[r];
        }
    }

    // f1 (linear term): 16 threads per sample, 4 iters each
    {
        const int s = tid >> 4, u = tid & 15;
        float f1 = 0.0f;
        #pragma unroll
        for (int i = 0; i < 4; ++i) f1 = fmaf(w1[u + 16 * i], xs[u + 16 * i][s], f1);
        for (int m = 1; m <= 8; m <<= 1) f1 += __shfl_xor(f1, m, 64);
        if (u == 0) f1s[s] = f1;
    }
    __syncthreads();

    if (tid < 32) {
        float s = red[0][tid] + red[1][tid] + red[2][tid] + red[3][tid]
                + red[4][tid] + red[5][tid] + red[6][tid] + red[7][tid];
        float f = fmaf(g0, w0[0], fmaf(g1, f1s[tid], s));
        out[s0 + tid] = 1.0f / (1.0f + __expf(-f));
    }
}

extern "C" void kernel_launch(void* const* d_in, const int* in_sizes, int n_in,
                              void* d_out, int out_size, void* d_ws, size_t ws_size,
                              hipStream_t stream)
{
    const float* X     = (const float*)d_in[0];
    const float* w0    = (const float*)d_in[1];
    const float* w1    = (const float*)d_in[2];
    const float* w2    = (const float*)d_in[3];
    const float* w3    = (const float*)d_in[4];
    const float* alpha = (const float*)d_in[5];
    float* out = (float*)d_out;

    char* ws = (char*)d_ws;
    short* Wp  = (short*)(ws + W_OFF);
    float2* et = (float2*)(ws + E_OFF);

    void* args[] = { (void*)&X, (void*)&w0, (void*)&w1, (void*)&w2, (void*)&w3,
                     (void*)&alpha, (void*)&Wp, (void*)&et, (void*)&out };

    hipLaunchCooperativeKernel((const void*)fused_kernel,
                               dim3(256), dim3(512), args, 0, stream);
}

// Round 7
// 19.876 us; speedup vs baseline: 3.3768x; 3.3768x over previous
//
#include <hip/hip_runtime.h>
#include <hip/hip_bf16.h>

// out = sigmoid( g0*w0 + g1*(X@w1) + g2*f2 + g3*f3 ), D=64, N=8192
// f3 via GEMM: monomial {a<=b<=c} w -> W[pair(b,c), a]; f3[n] = sum_p y_p * (X@W^T)[n,p], y_p = x_j x_k
// f2 folded into epilogue: part += (g3*S[n,p] + g2*w2eff[p]) * y_p
// R7: element-parallel build (149K threads, closed-form decode, 1 gather/thread);
//     poly = R6's pipelined loop as a standalone kernel (no cooperative sync).

#define DD 64
#define NPAIR 2080
#define NTILES 130
#define PTILES 146   // 130 real + 16 zero dummy tiles (branchless 2-deep prefetch, max idx 145)

typedef __attribute__((ext_vector_type(8))) short short8;
typedef __attribute__((ext_vector_type(4))) float f32x4;

// ws layout (bytes)
#define W_OFF  0u         // bf16 packed [146][2][64][8] = 299008
#define E_OFF  299008u    // float2 {g2*w2eff, jk} [146*16] = 18688

__device__ __forceinline__ short f2bf(float v) {
    __hip_bfloat16 h = __float2bfloat16(v);
    return (short)__builtin_bit_cast(unsigned short, h);
}

__device__ __forceinline__ void compute_gates(const float* __restrict__ alpha,
                                              float& g0, float& g1, float& g2, float& g3) {
    float a0 = alpha[0], a1 = alpha[1], a2 = alpha[2], a3 = alpha[3];
    float m = fmaxf(fmaxf(a0, a1), fmaxf(a2, a3));
    float e0 = __expf(a0 - m), e1 = __expf(a1 - m);
    float e2 = __expf(a2 - m), e3 = __expf(a3 - m);
    float inv = 1.0f / (e0 + e1 + e2 + e3);
    g0 = e0 * inv; g1 = e1 * inv; g2 = e2 * inv; g3 = e3 * inv;
}

// closed-form: pair row (j<=k lex) -> j, via inverse triangular number + 1-step fix
// base(j) = j*(129-j)/2
__device__ __forceinline__ int row2j(int row) {
    float disc = 16641.0f - 8.0f * (float)row;       // 129^2 - 8*row
    int j = (int)((129.0f - sqrtf(disc)) * 0.5f);
    if (j > 0 && row < (j * (129 - j)) / 2) --j;
    if (row >= ((j + 1) * (128 - j)) / 2) ++j;
    return j;
}

// ---------- build: one thread per packed short of Wp ----------
// Packed layout: idx = nt*1024 + (a>>5)*512 + ((row&15) + 16*((a>>3)&3))*8 + (a&7)
// grid covers PTILES*1024 threads; thread t also builds et[t] for t < PTILES*16.
__global__ __launch_bounds__(256) void build_kernel(
    const float* __restrict__ w2, const float* __restrict__ w3,
    const float* __restrict__ alpha, short* __restrict__ Wp, float2* __restrict__ et)
{
    const int t = blockIdx.x * 256 + threadIdx.x;    // < PTILES*1024 = 149504
    const int nt   = t >> 10;
    const int rem  = t & 1023;
    const int half = rem >> 9;
    const int fl   = (rem >> 3) & 63;                // fragment lane 0..63
    const int e    = t & 7;
    const int row  = nt * 16 + (fl & 15);            // pair row 0..2335
    const int a    = half * 32 + (fl >> 4) * 8 + e;  // monomial smallest index (col)

    float w = 0.0f;
    if (row < NPAIR) {
        const int j = row2j(row);
        const int k = j + row - (j * (129 - j)) / 2;
        if (a <= j) {
            if (a == j) {
                w = (j == k) ? w3[j]                                              // x_j^3
                             : w3[64 + 63 * j - (j * (j - 1)) / 2 + (k - j - 1)]; // x_j^2 x_k
            } else if (j == k) {                                                  // x_a x_j^2
                w = w3[64 + 2016 + 63 * a - (a * (a - 1)) / 2 + (j - a - 1)];
            } else {                                                              // x_a x_j x_k
                const int tb = 41664 - ((64 - a) * (63 - a) * (62 - a)) / 6;
                const int po = ((126 - a - j) * (j - a - 1)) / 2 + (k - j - 1);
                w = w3[4096 + tb + po];
            }
        }
    }
    Wp[t] = f2bf(w);

    if (t < PTILES * 16) {                           // et row t
        float2 ev; ev.x = 0.0f; ev.y = __uint_as_float(0u);
        if (t < NPAIR) {
            float g0, g1, g2, g3;
            compute_gates(alpha, g0, g1, g2, g3);
            const int j = row2j(t);
            const int k = j + t - (j * (129 - j)) / 2;
            float w2e = (j == k) ? w2[j] : w2[64 + 63 * j - (j * (j - 1)) / 2 + (k - j - 1)];
            ev.x = g2 * w2e;
            ev.y = __uint_as_float(((unsigned)j << 8) | (unsigned)k);
        }
        et[t] = ev;
    }
}

// ---------- poly: fused GEMM(X@W^T) epilogue + f1 + sigmoid ----------
// 256 blocks x 512 thr (8 waves); block owns 32 samples; wave wv walks tiles wv, wv+8, ...
__global__ __launch_bounds__(512) void poly_mfma(
    const float* __restrict__ X,
    const float* __restrict__ w0,
    const float* __restrict__ w1,
    const float* __restrict__ alpha,
    const short* __restrict__ Wp,
    const float2* __restrict__ et,
    float* __restrict__ out)
{
    __shared__ float xs[DD][36];     // transposed tile: xs[dim][sample]
    __shared__ float red[8][32];
    __shared__ float f1s[32];

    const int tid = threadIdx.x;
    const int lane = tid & 63, wv = tid >> 6;
    const int s0 = blockIdx.x * 32;

    float g0, g1, g2, g3;
    compute_gates(alpha, g0, g1, g2, g3);

    for (int idx = tid; idx < 32 * 64; idx += 512) {
        xs[idx & 63][idx >> 6] = X[(size_t)s0 * 64 + idx];
    }

    // A fragments straight from global X (L2-warm), converted in-register
    const int arow = lane & 15, akg = lane >> 4;
    const float* xr0 = X + (size_t)(s0 + arow) * 64 + 8 * akg;
    const float* xr1 = X + (size_t)(s0 + 16 + arow) * 64 + 8 * akg;
    short8 a0m0, a1m0, a0m1, a1m1;
    {
        f32x4 p0 = *(const f32x4*)(xr0);
        f32x4 p1 = *(const f32x4*)(xr0 + 4);
        f32x4 q0 = *(const f32x4*)(xr0 + 32);
        f32x4 q1 = *(const f32x4*)(xr0 + 36);
        f32x4 r0 = *(const f32x4*)(xr1);
        f32x4 r1 = *(const f32x4*)(xr1 + 4);
        f32x4 s0v = *(const f32x4*)(xr1 + 32);
        f32x4 s1v = *(const f32x4*)(xr1 + 36);
        #pragma unroll
        for (int e = 0; e < 4; ++e) {
            a0m0[e] = f2bf(p0[e]); a0m0[4 + e] = f2bf(p1[e]);
            a1m0[e] = f2bf(q0[e]); a1m0[4 + e] = f2bf(q1[e]);
            a0m1[e] = f2bf(r0[e]); a0m1[4 + e] = f2bf(r1[e]);
            a1m1[e] = f2bf(s0v[e]); a1m1[4 + e] = f2bf(s1v[e]);
        }
    }

    __syncthreads();

    // slots: A = nt (compute), B = nt+8 (next), C = nt+16 (prefetch). Dummy tiles are zeros.
    const short* wb = Wp + wv * 1024 + lane * 8;
    const float2* ep = et + wv * 16 + arow;

    short8 bA0 = *(const short8*)wb;
    short8 bA1 = *(const short8*)(wb + 512);
    float2 eA = *ep;
    short8 bB0 = *(const short8*)(wb + 8192);
    short8 bB1 = *(const short8*)(wb + 8192 + 512);
    float2 eB = *(ep + 128);
    wb += 16384; ep += 256;

    unsigned jkA = __float_as_uint(eA.y);
    float bpA = eA.x;
    f32x4 xj0 = *(const f32x4*)&xs[jkA >> 8][4 * akg];
    f32x4 xk0 = *(const f32x4*)&xs[jkA & 255][4 * akg];
    f32x4 xj1 = *(const f32x4*)&xs[jkA >> 8][16 + 4 * akg];
    f32x4 xk1 = *(const f32x4*)&xs[jkA & 255][16 + 4 * akg];

    float part0[4] = {0, 0, 0, 0}, part1[4] = {0, 0, 0, 0};
    const int niter = (NTILES - wv + 7) >> 3;        // 16 or 17

    #pragma unroll 2
    for (int it = 0; it < niter; ++it) {
        short8 bC0 = *(const short8*)wb;             // prefetch slot C
        short8 bC1 = *(const short8*)(wb + 512);
        float2 eC = *ep;
        wb += 8192; ep += 128;

        const unsigned jkB = __float_as_uint(eB.y);  // pipeline next iter's LDS reads
        const float bpB = eB.x;
        f32x4 nxj0 = *(const f32x4*)&xs[jkB >> 8][4 * akg];
        f32x4 nxk0 = *(const f32x4*)&xs[jkB & 255][4 * akg];
        f32x4 nxj1 = *(const f32x4*)&xs[jkB >> 8][16 + 4 * akg];
        f32x4 nxk1 = *(const f32x4*)&xs[jkB & 255][16 + 4 * akg];

        f32x4 c0 = {0, 0, 0, 0}, c1 = {0, 0, 0, 0};
        c0 = __builtin_amdgcn_mfma_f32_16x16x32_bf16(a0m0, bA0, c0, 0, 0, 0);
        c0 = __builtin_amdgcn_mfma_f32_16x16x32_bf16(a1m0, bA1, c0, 0, 0, 0);
        c1 = __builtin_amdgcn_mfma_f32_16x16x32_bf16(a0m1, bA0, c1, 0, 0, 0);
        c1 = __builtin_amdgcn_mfma_f32_16x16x32_bf16(a1m1, bA1, c1, 0, 0, 0);

        #pragma unroll
        for (int r = 0; r < 4; ++r) {
            float t0 = fmaf(g3, c0[r], bpA);
            part0[r] = fmaf(t0, xj0[r] * xk0[r], part0[r]);
            float t1 = fmaf(g3, c1[r], bpA);
            part1[r] = fmaf(t1, xj1[r] * xk1[r], part1[r]);
        }

        bA0 = bB0; bA1 = bB1; bB0 = bC0; bB1 = bC1;
        bpA = bpB; eB = eC;
        xj0 = nxj0; xk0 = nxk0; xj1 = nxj1; xk1 = nxk1;
    }

    // reduce across the 16 pair-columns (lane bits 0..3)
    #pragma unroll
    for (int r = 0; r < 4; ++r) {
        float v0 = part0[r], v1 = part1[r];
        for (int m = 1; m <= 8; m <<= 1) {
            v0 += __shfl_xor(v0, m, 64);
            v1 += __shfl_xor(v1, m, 64);
        }
        part0[r] = v0; part1[r] = v1;
    }
    if ((lane & 15) == 0) {
        const int rb = 4 * (lane >> 4);
        #pragma unroll
        for (int r = 0; r < 4; ++r) {
            red[wv][rb + r] = part0[r];
            red[wv][16 + rb + r] = part1[r];
        }
    }

    // f1 (linear term): 16 threads per sample, 4 iters each
    {
        const int s = tid >> 4, u = tid & 15;
        float f1 = 0.0f;
        #pragma unroll
        for (int i = 0; i < 4; ++i) f1 = fmaf(w1[u + 16 * i], xs[u + 16 * i][s], f1);
        for (int m = 1; m <= 8; m <<= 1) f1 += __shfl_xor(f1, m, 64);
        if (u == 0) f1s[s] = f1;
    }
    __syncthreads();

    if (tid < 32) {
        float s = red[0][tid] + red[1][tid] + red[2][tid] + red[3][tid]
                + red[4][tid] + red[5][tid] + red[6][tid] + red[7][tid];
        float f = fmaf(g0, w0[0], fmaf(g1, f1s[tid], s));
        out[s0 + tid] = 1.0f / (1.0f + __expf(-f));
    }
}

extern "C" void kernel_launch(void* const* d_in, const int* in_sizes, int n_in,
                              void* d_out, int out_size, void* d_ws, size_t ws_size,
                              hipStream_t stream)
{
    const float* X     = (const float*)d_in[0];
    const float* w0    = (const float*)d_in[1];
    const float* w1    = (const float*)d_in[2];
    const float* w2    = (const float*)d_in[3];
    const float* w3    = (const float*)d_in[4];
    const float* alpha = (const float*)d_in[5];
    float* out = (float*)d_out;

    char* ws = (char*)d_ws;
    short* Wp  = (short*)(ws + W_OFF);
    float2* et = (float2*)(ws + E_OFF);

    const int N = in_sizes[0] / DD;          // 8192

    build_kernel<<<(PTILES * 1024) / 256, 256, 0, stream>>>(w2, w3, alpha, Wp, et);
    poly_mfma<<<N / 32, 512, 0, stream>>>(X, w0, w1, alpha, Wp, et, out);
}